// Round 1
// baseline (1542.989 us; speedup 1.0000x reference)
//
#include <hip/hip_runtime.h>

// ---- problem constants (fixed by reference) ----
constexpr int BATCH = 8;     // clips
constexpr int SEQ   = 8;     // frames
constexpr int CCH   = 1024;  // inplanes C
constexpr int PPL   = 512;   // planes P
constexpr int HWSZ  = 196;   // 14*14
constexpr int LSZ   = SEQ * HWSZ;  // 1568
constexpr float BN_EPS = 1e-5f;
constexpr long TOT = (long)BATCH * SEQ * CCH * HWSZ;  // 12,845,056

// =====================================================================
// Generic fp32 tiled GEMM: C[M,N] = opA[M,K] @ opB[K,N] (+bias) (+accum)
//  AMODE 0: opA[m,k] = A[m*lda + k]      (row-major [M,K])
//  AMODE 1: opA[m,k] = A[k*lda + m]      (A stored [K,M] -> computes A^T)
//  BMODE 0: opB[k,n] = B[k*ldb + n]      (row-major [K,N])
//  BMODE 1: opB[k,n] = B[n*ldb + k]      (B stored [N,K] -> computes B^T)
// Block: 128x128 tile, K-step 8, 256 threads, 8x8 micro-tile per thread.
// Requires K % 8 == 0, N % 4 == 0, M % 4 == 0 (true for all our shapes).
// =====================================================================
template<int AMODE, int BMODE, bool BIAS, bool ACCUM>
__global__ __launch_bounds__(256)
void gemm_kernel(const float* __restrict__ A, long asb, int lda,
                 const float* __restrict__ B, long bsb, int ldb,
                 float* __restrict__ Cc, long csb, int ldc,
                 const float* __restrict__ bias,
                 int M, int N, int K)
{
    __shared__ __align__(16) float As[8][128];
    __shared__ __align__(16) float Bs[8][128];

    const int bz = blockIdx.z;
    A  += (long)bz * asb;
    B  += (long)bz * bsb;
    Cc += (long)bz * csb;

    const int m0 = blockIdx.y * 128;
    const int n0 = blockIdx.x * 128;
    const int tid = threadIdx.x;
    const int tx = tid & 15;      // 0..15  -> n
    const int ty = tid >> 4;      // 0..15  -> m

    float acc[8][8];
    #pragma unroll
    for (int i = 0; i < 8; ++i)
        #pragma unroll
        for (int j = 0; j < 8; ++j) acc[i][j] = 0.0f;

    for (int k0 = 0; k0 < K; k0 += 8) {
        // ---- stage A tile -> As[kk][mm] ----
        if (AMODE == 0) {
            const int ar = tid >> 1;          // mm 0..127
            const int ac = (tid & 1) * 4;     // kk base {0,4}
            float4 v = make_float4(0.f, 0.f, 0.f, 0.f);
            if (m0 + ar < M)
                v = *(const float4*)&A[(long)(m0 + ar) * lda + k0 + ac];
            As[ac + 0][ar] = v.x; As[ac + 1][ar] = v.y;
            As[ac + 2][ar] = v.z; As[ac + 3][ar] = v.w;
        } else {
            const int ar = tid >> 5;          // kk 0..7
            const int ac = (tid & 31) * 4;    // mm base
            float4 v = make_float4(0.f, 0.f, 0.f, 0.f);
            if (m0 + ac < M)
                v = *(const float4*)&A[(long)(k0 + ar) * lda + m0 + ac];
            *(float4*)&As[ar][ac] = v;
        }
        // ---- stage B tile -> Bs[kk][nn] ----
        if (BMODE == 0) {
            const int br = tid >> 5;          // kk 0..7
            const int bc = (tid & 31) * 4;    // nn base
            float4 v = make_float4(0.f, 0.f, 0.f, 0.f);
            if (n0 + bc < N)
                v = *(const float4*)&B[(long)(k0 + br) * ldb + n0 + bc];
            *(float4*)&Bs[br][bc] = v;
        } else {
            const int br = tid >> 1;          // nn 0..127
            const int bc = (tid & 1) * 4;     // kk base {0,4}
            float4 v = make_float4(0.f, 0.f, 0.f, 0.f);
            if (n0 + br < N)
                v = *(const float4*)&B[(long)(n0 + br) * ldb + k0 + bc];
            Bs[bc + 0][br] = v.x; Bs[bc + 1][br] = v.y;
            Bs[bc + 2][br] = v.z; Bs[bc + 3][br] = v.w;
        }
        __syncthreads();

        #pragma unroll
        for (int kk = 0; kk < 8; ++kk) {
            const float4 a0 = *(const float4*)&As[kk][ty * 4];
            const float4 a1 = *(const float4*)&As[kk][ty * 4 + 64];
            const float4 b0 = *(const float4*)&Bs[kk][tx * 4];
            const float4 b1 = *(const float4*)&Bs[kk][tx * 4 + 64];
            const float am[8] = {a0.x, a0.y, a0.z, a0.w, a1.x, a1.y, a1.z, a1.w};
            const float bn[8] = {b0.x, b0.y, b0.z, b0.w, b1.x, b1.y, b1.z, b1.w};
            #pragma unroll
            for (int i = 0; i < 8; ++i)
                #pragma unroll
                for (int j = 0; j < 8; ++j)
                    acc[i][j] += am[i] * bn[j];
        }
        __syncthreads();
    }

    // ---- epilogue: (optional accum) + bias, float4 stores ----
    #pragma unroll
    for (int i = 0; i < 8; ++i) {
        const int mrow = m0 + (i >> 2) * 64 + ty * 4 + (i & 3);
        if (mrow >= M) continue;
        const float bv = BIAS ? bias[mrow] : 0.0f;
        #pragma unroll
        for (int jh = 0; jh < 2; ++jh) {
            const int ncol = n0 + jh * 64 + tx * 4;
            if (ncol + 3 < N) {
                float4 r;
                r.x = acc[i][jh * 4 + 0] + bv;
                r.y = acc[i][jh * 4 + 1] + bv;
                r.z = acc[i][jh * 4 + 2] + bv;
                r.w = acc[i][jh * 4 + 3] + bv;
                float* cp = &Cc[(long)mrow * ldc + ncol];
                if (ACCUM) {
                    const float4 o = *(const float4*)cp;
                    r.x += o.x; r.y += o.y; r.z += o.z; r.w += o.w;
                }
                *(float4*)cp = r;
            } else {
                #pragma unroll
                for (int jj = 0; jj < 4; ++jj) {
                    const int nc = ncol + jj;
                    if (nc < N) {
                        float r = acc[i][jh * 4 + jj] + bv;
                        if (ACCUM) r += Cc[(long)mrow * ldc + nc];
                        Cc[(long)mrow * ldc + nc] = r;
                    }
                }
            }
        }
    }
}

// ---- concat t_w/p_w/g_w -> Wtpg [1536,1024], biases -> btpg[1536] ----
__global__ void concat_w(const float* __restrict__ tw, const float* __restrict__ pw,
                         const float* __restrict__ gw, const float* __restrict__ tb,
                         const float* __restrict__ pb, const float* __restrict__ gb,
                         float* __restrict__ W, float* __restrict__ bb)
{
    const int i = blockIdx.x * 256 + threadIdx.x;
    const int sz = PPL * CCH;  // 512*1024
    if (i < sz)            W[i] = tw[i];
    else if (i < 2 * sz)   W[i] = pw[i - sz];
    else if (i < 3 * sz)   W[i] = gw[i - 2 * sz];
    if (i < PPL)                bb[i] = tb[i];
    else if (i < 2 * PPL)       bb[i] = pb[i - PPL];
    else if (i < 3 * PPL)       bb[i] = gb[i - 2 * PPL];
}

// ---- x [b*n, c, hw] -> xt [b, c, n*hw] ----
__global__ void transpose_x(const float* __restrict__ x, float* __restrict__ xt)
{
    const long i4 = (long)blockIdx.x * 256 + threadIdx.x;
    const long idx = i4 * 4;
    if (idx >= TOT) return;
    const int b  = (int)(idx / ((long)CCH * LSZ));
    const int r  = (int)(idx % ((long)CCH * LSZ));
    const int c  = r / LSZ;
    const int l  = r % LSZ;
    const int n  = l / HWSZ;
    const int hw = l % HWSZ;
    const float4 v = *(const float4*)&x[((long)(b * SEQ + n) * CCH + c) * HWSZ + hw];
    *(float4*)&xt[idx] = v;
}

// ---- row softmax over att rows of length LSZ, in place ----
__global__ __launch_bounds__(256)
void softmax_rows(float* __restrict__ att)
{
    const int row = blockIdx.x;               // 0 .. 8*1568-1
    float* r = att + (long)row * LSZ;
    const int tid = threadIdx.x;

    float v[7];
    float mx = -1e30f;
    #pragma unroll
    for (int it = 0; it < 7; ++it) {
        const int m = tid + it * 256;
        v[it] = (m < LSZ) ? r[m] : -1e30f;
        mx = fmaxf(mx, v[it]);
    }
    __shared__ float red[256];
    red[tid] = mx; __syncthreads();
    for (int s = 128; s > 0; s >>= 1) {
        if (tid < s) red[tid] = fmaxf(red[tid], red[tid + s]);
        __syncthreads();
    }
    mx = red[0]; __syncthreads();

    float sum = 0.0f;
    #pragma unroll
    for (int it = 0; it < 7; ++it) {
        const int m = tid + it * 256;
        v[it] = (m < LSZ) ? __expf(v[it] - mx) : 0.0f;
        sum += v[it];
    }
    red[tid] = sum; __syncthreads();
    for (int s = 128; s > 0; s >>= 1) {
        if (tid < s) red[tid] += red[tid + s];
        __syncthreads();
    }
    const float inv = 1.0f / red[0];
    #pragma unroll
    for (int it = 0; it < 7; ++it) {
        const int m = tid + it * 256;
        if (m < LSZ) r[m] = v[it] * inv;
    }
}

// ---- per-channel batchnorm stats over (b, l): scale/shift form ----
__global__ __launch_bounds__(256)
void bn_stats(const float* __restrict__ y, const float* __restrict__ gamma,
              const float* __restrict__ beta, float* __restrict__ scale,
              float* __restrict__ shift)
{
    const int c = blockIdx.x;
    const int tid = threadIdx.x;
    float s1 = 0.f, s2 = 0.f;
    for (int b = 0; b < BATCH; ++b) {
        const float* row = y + ((long)(b * CCH + c)) * LSZ;
        for (int m = tid; m < LSZ; m += 256) {
            const float t = row[m];
            s1 += t; s2 += t * t;
        }
    }
    __shared__ float r1[256], r2[256];
    r1[tid] = s1; r2[tid] = s2; __syncthreads();
    for (int s = 128; s > 0; s >>= 1) {
        if (tid < s) { r1[tid] += r1[tid + s]; r2[tid] += r2[tid + s]; }
        __syncthreads();
    }
    if (tid == 0) {
        const float cnt = (float)(BATCH * LSZ);
        const float mean = r1[0] / cnt;
        const float var = r2[0] / cnt - mean * mean;
        const float istd = rsqrtf(var + BN_EPS);
        const float sc = gamma[c] * istd;
        scale[c] = sc;
        shift[c] = beta[c] - mean * sc;
    }
}

// ---- out[b,n,c,hw] = y[b,c,n*hw]*scale[c] + shift[c] + x[b,n,c,hw] ----
__global__ void epilogue_k(const float* __restrict__ y, const float* __restrict__ x,
                           const float* __restrict__ scale, const float* __restrict__ shift,
                           float* __restrict__ out)
{
    const long i4 = (long)blockIdx.x * 256 + threadIdx.x;
    const long idx = i4 * 4;
    if (idx >= TOT) return;
    const int b  = (int)(idx / ((long)SEQ * CCH * HWSZ));
    const int r  = (int)(idx % ((long)SEQ * CCH * HWSZ));
    const int n  = r / (CCH * HWSZ);
    const int r2 = r % (CCH * HWSZ);
    const int c  = r2 / HWSZ;
    const int hw = r2 % HWSZ;
    const float4 yv = *(const float4*)&y[((long)(b * CCH + c)) * LSZ + n * HWSZ + hw];
    const float4 xv = *(const float4*)&x[idx];
    const float sc = scale[c], sh = shift[c];
    float4 o;
    o.x = yv.x * sc + sh + xv.x;
    o.y = yv.y * sc + sh + xv.y;
    o.z = yv.z * sc + sh + xv.z;
    o.w = yv.w * sc + sh + xv.w;
    *(float4*)&out[idx] = o;
}

extern "C" void kernel_launch(void* const* d_in, const int* in_sizes, int n_in,
                              void* d_out, int out_size, void* d_ws, size_t ws_size,
                              hipStream_t stream)
{
    const float* x     = (const float*)d_in[0];
    const float* t_w   = (const float*)d_in[1];
    const float* t_b   = (const float*)d_in[2];
    const float* p_w   = (const float*)d_in[3];
    const float* p_b   = (const float*)d_in[4];
    const float* g_w   = (const float*)d_in[5];
    const float* g_b   = (const float*)d_in[6];
    const float* w1_w  = (const float*)d_in[7];
    const float* w1_b  = (const float*)d_in[8];
    const float* w2_w  = (const float*)d_in[9];
    const float* w2_b  = (const float*)d_in[10];
    const float* gamma = (const float*)d_in[11];
    const float* beta  = (const float*)d_in[12];
    float* out = (float*)d_out;

    // ---- workspace layout (floats) ----
    float* ws = (float*)d_ws;
    float* Wtpg = ws;                                  // 1536*1024
    float* btpg = Wtpg + (long)1536 * 1024;            // 1536
    float* xt   = btpg + 1536;                         // 8*1024*1568 (later reused as y)
    float* tpg  = xt + (long)BATCH * CCH * LSZ;        // 8*1536*1568
    float* att  = tpg + (long)BATCH * 1536 * LSZ;      // 8*1568*1568
    float* scale = att + (long)BATCH * LSZ * LSZ;      // 1024
    float* shift = scale + CCH;                        // 1024
    float* y  = xt;                                    // alias: xt dead after G1
    float* t_ = tpg;                                   // rows 0..511 per batch
    float* p_ = tpg + (long)PPL * LSZ;                 // rows 512..1023
    float* g_ = tpg + (long)2 * PPL * LSZ;             // rows 1024..1535
    float* x2 = p_;                                    // alias: p dead after att GEMM

    const long sTPG = (long)1536 * LSZ;   // per-batch stride of tpg
    const long sX   = (long)CCH * LSZ;    // per-batch stride of xt / y
    const long sATT = (long)LSZ * LSZ;    // per-batch stride of att

    // 1) concat weights
    concat_w<<<6144, 256, 0, stream>>>(t_w, p_w, g_w, t_b, p_b, g_b, Wtpg, btpg);
    // 2) x -> xt  [b, c, l]
    transpose_x<<<(int)(TOT / 4 / 256), 256, 0, stream>>>(x, xt);
    // 3) tpg = Wtpg @ xt  (+bias)   M=1536 N=1568 K=1024
    gemm_kernel<0, 0, true, false><<<dim3(13, 12, BATCH), 256, 0, stream>>>(
        Wtpg, 0, 1024, xt, sX, LSZ, tpg, sTPG, LSZ, btpg, 1536, LSZ, 1024);
    // 4) att = t^T @ p              M=1568 N=1568 K=512
    gemm_kernel<1, 0, false, false><<<dim3(13, 13, BATCH), 256, 0, stream>>>(
        t_, sTPG, LSZ, p_, sTPG, LSZ, att, sATT, LSZ, nullptr, LSZ, LSZ, PPL);
    // 5) softmax rows of att (in place)
    softmax_rows<<<BATCH * LSZ, 256, 0, stream>>>(att);
    // 6) x2 = g @ att^T             M=512 N=1568 K=1568   (x2 overwrites p region)
    gemm_kernel<0, 1, false, false><<<dim3(13, 4, BATCH), 256, 0, stream>>>(
        g_, sTPG, LSZ, att, sATT, LSZ, x2, sTPG, LSZ, nullptr, PPL, LSZ, LSZ);
    // 7) y = W1 @ g + b1            M=1024 N=1568 K=512   (y overwrites xt)
    gemm_kernel<0, 0, true, false><<<dim3(13, 8, BATCH), 256, 0, stream>>>(
        w1_w, 0, PPL, g_, sTPG, LSZ, y, sX, LSZ, w1_b, CCH, LSZ, PPL);
    // 8) y += W2 @ x2 + b2
    gemm_kernel<0, 0, true, true><<<dim3(13, 8, BATCH), 256, 0, stream>>>(
        w2_w, 0, PPL, x2, sTPG, LSZ, y, sX, LSZ, w2_b, CCH, LSZ, PPL);
    // 9) BN stats -> scale/shift per channel
    bn_stats<<<CCH, 256, 0, stream>>>(y, gamma, beta, scale, shift);
    // 10) out = y*scale + shift + x  (with [b,c,l] -> [b,n,c,hw] permute)
    epilogue_k<<<(int)(TOT / 4 / 256), 256, 0, stream>>>(y, x, scale, shift, out);
}

// Round 2
// 287.010 us; speedup vs baseline: 5.3761x; 5.3761x over previous
//
#include <hip/hip_runtime.h>

using half8   = __attribute__((ext_vector_type(8))) _Float16;
using floatx4 = __attribute__((ext_vector_type(4))) float;

constexpr int BATCH = 8, SEQn = 8, CCH = 1024, PPL = 512, HWSZ = 196;
constexpr int LSZ = 1568;            // SEQ * H * W
constexpr int LP  = 1664;            // padded L: 13*128 = 26*64
constexpr float BN_EPS = 1e-5f;
constexpr long TOT = (long)BATCH * SEQn * CCH * HWSZ;  // 12,845,056

// async global->LDS, 16B per lane; lds must be wave-uniform base
__device__ __forceinline__ void gload16(const void* g, void* lds) {
    __builtin_amdgcn_global_load_lds(
        (const __attribute__((address_space(1))) unsigned int*)g,
        (__attribute__((address_space(3))) unsigned int*)lds, 16, 0, 0);
}

// =====================================================================
// fp16 MFMA GEMM, m97-style: 128x128 tile, BK=64, 4 waves (2x2), each wave
// 64x64 via 4x4 fragments of 16x16x32_f16. Both operands stored [rows, K]
// row-major (A rows = M, B rows = N), K contiguous, 16B-chunk loadable.
// LDS: linear dest (global_load_lds) + source chunk pre-swizzle c^=(r&7),
// reads undo the same XOR -> conflict-free ds_read_b128 (rule #21).
// All buffers padded so staging needs no guards.
// EPI: 0 = tpg (t/p transposed fp16 +bias, g normal+transposed fp16 +bias)
//      1 = att fp32 normal
//      2 = x2T fp16 into gx2T cols 512..1023
//      3 = y fp16 normal + bias
// =====================================================================
template<int EPI>
__global__ __launch_bounds__(256)
void hgemm(const _Float16* __restrict__ A, long asb, int lda,
           const _Float16* __restrict__ B, long bsb, int ldb,
           void* __restrict__ C0p, long c0s,
           void* __restrict__ C1p, long c1s,
           void* __restrict__ C2p, long c2s,
           const float* __restrict__ bias, int K)
{
    __shared__ _Float16 As[128 * 64];
    __shared__ _Float16 Bs[128 * 64];
    const int bz = blockIdx.z;
    const _Float16* Ab = A + (long)bz * asb;
    const _Float16* Bb = B + (long)bz * bsb;
    const int m0 = blockIdx.y * 128;
    const int n0 = blockIdx.x * 128;
    const int tid = threadIdx.x;
    const int w   = tid >> 6;
    const int ln  = tid & 63;
    const int wm  = w >> 1, wn = w & 1;

    floatx4 acc[4][4];
    #pragma unroll
    for (int i = 0; i < 4; ++i)
        #pragma unroll
        for (int j = 0; j < 4; ++j) acc[i][j] = {0.f, 0.f, 0.f, 0.f};

    // staging offsets: chunk CH=(i*4+w)*64+ln; row r=CH>>3, chunk c=CH&7;
    // source chunk pre-swizzled: c ^ (r&7)
    long aoff[4], boff[4]; int ldso[4];
    #pragma unroll
    for (int i = 0; i < 4; ++i) {
        const int CH = (i * 4 + w) * 64 + ln;
        const int r = CH >> 3, c = CH & 7;
        const int sc = (c ^ (r & 7)) << 3;       // element offset in row
        aoff[i] = (long)(m0 + r) * lda + sc;
        boff[i] = (long)(n0 + r) * ldb + sc;
        ldso[i] = (i * 4 + w) * 512;             // 1KB per wave-issue
    }

    for (int k0 = 0; k0 < K; k0 += 64) {
        #pragma unroll
        for (int i = 0; i < 4; ++i) {
            gload16(Ab + aoff[i] + k0, As + ldso[i]);
            gload16(Bb + boff[i] + k0, Bs + ldso[i]);
        }
        __syncthreads();   // compiler inserts vmcnt(0) drain before barrier
        #pragma unroll
        for (int ks = 0; ks < 2; ++ks) {
            half8 af[4], bf[4];
            #pragma unroll
            for (int mi = 0; mi < 4; ++mi) {
                const int r = wm * 64 + mi * 16 + (ln & 15);
                const int c = ks * 4 + (ln >> 4);
                af[mi] = *(const half8*)&As[r * 64 + ((c ^ (r & 7)) << 3)];
            }
            #pragma unroll
            for (int ni = 0; ni < 4; ++ni) {
                const int r = wn * 64 + ni * 16 + (ln & 15);
                const int c = ks * 4 + (ln >> 4);
                bf[ni] = *(const half8*)&Bs[r * 64 + ((c ^ (r & 7)) << 3)];
            }
            #pragma unroll
            for (int mi = 0; mi < 4; ++mi)
                #pragma unroll
                for (int ni = 0; ni < 4; ++ni)
                    acc[mi][ni] = __builtin_amdgcn_mfma_f32_16x16x32_f16(
                        af[mi], bf[ni], acc[mi][ni], 0, 0, 0);
        }
        __syncthreads();
    }

    // C/D layout (m89-verified): col = ln&15, row = (ln>>4)*4 + reg
    const int cm = wm * 64 + (ln >> 4) * 4;
    const int cn = wn * 64 + (ln & 15);

    if constexpr (EPI == 0) {
        if (m0 < 1024) {   // t or p region -> transposed store [L, 512]
            _Float16* T = (_Float16*)C0p + (long)bz * c0s
                          + (m0 >= 512 ? (long)LP * PPL : 0);
            const int mb = m0 & 511;
            #pragma unroll
            for (int mi = 0; mi < 4; ++mi) {
                const int gmF = m0 + cm + mi * 16;
                const float4 bv = *(const float4*)&bias[gmF];
                const int gm = mb + cm + mi * 16;
                #pragma unroll
                for (int ni = 0; ni < 4; ++ni) {
                    const int gn = n0 + cn + ni * 16;
                    union { _Float16 h[4]; uint2 u; } pk;
                    pk.h[0] = (_Float16)(acc[mi][ni][0] + bv.x);
                    pk.h[1] = (_Float16)(acc[mi][ni][1] + bv.y);
                    pk.h[2] = (_Float16)(acc[mi][ni][2] + bv.z);
                    pk.h[3] = (_Float16)(acc[mi][ni][3] + bv.w);
                    *(uint2*)&T[(long)gn * PPL + gm] = pk.u;
                }
            }
        } else {           // g region: normal [512, LP] + transposed into gx2T
            _Float16* G  = (_Float16*)C1p + (long)bz * c1s;
            _Float16* GT = (_Float16*)C2p + (long)bz * c2s;
            #pragma unroll
            for (int mi = 0; mi < 4; ++mi) {
                const int gmF = m0 + cm + mi * 16;
                const float4 bv = *(const float4*)&bias[gmF];
                const int q = gmF - 1024;
                #pragma unroll
                for (int ni = 0; ni < 4; ++ni) {
                    const int gn = n0 + cn + ni * 16;
                    union { _Float16 h[4]; uint2 u; } pk;
                    pk.h[0] = (_Float16)(acc[mi][ni][0] + bv.x);
                    pk.h[1] = (_Float16)(acc[mi][ni][1] + bv.y);
                    pk.h[2] = (_Float16)(acc[mi][ni][2] + bv.z);
                    pk.h[3] = (_Float16)(acc[mi][ni][3] + bv.w);
                    *(uint2*)&GT[(long)gn * 1024 + q] = pk.u;
                    // g feeds GEMM3's K dim -> zero-clamp the L-tail (0*NaN hazard)
                    const bool ok = gn < LSZ;
                    G[(long)(q + 0) * LP + gn] = ok ? pk.h[0] : (_Float16)0.f;
                    G[(long)(q + 1) * LP + gn] = ok ? pk.h[1] : (_Float16)0.f;
                    G[(long)(q + 2) * LP + gn] = ok ? pk.h[2] : (_Float16)0.f;
                    G[(long)(q + 3) * LP + gn] = ok ? pk.h[3] : (_Float16)0.f;
                }
            }
        }
    } else if constexpr (EPI == 1) {   // att fp32
        float* C = (float*)C0p + (long)bz * c0s;
        #pragma unroll
        for (int mi = 0; mi < 4; ++mi) {
            const int gm = m0 + cm + mi * 16;
            #pragma unroll
            for (int ni = 0; ni < 4; ++ni) {
                const int gn = n0 + cn + ni * 16;
                #pragma unroll
                for (int j = 0; j < 4; ++j)
                    C[(long)(gm + j) * LP + gn] = acc[mi][ni][j];
            }
        }
    } else if constexpr (EPI == 2) {   // x2T fp16 into gx2T[:, 512:1024]
        _Float16* C = (_Float16*)C0p + (long)bz * c0s + 512;
        #pragma unroll
        for (int mi = 0; mi < 4; ++mi) {
            const int gm = m0 + cm + mi * 16;
            #pragma unroll
            for (int ni = 0; ni < 4; ++ni) {
                const int gn = n0 + cn + ni * 16;
                #pragma unroll
                for (int j = 0; j < 4; ++j)
                    C[(long)(gm + j) * 1024 + gn] = (_Float16)acc[mi][ni][j];
            }
        }
    } else {                            // EPI 3: y fp16 + bias
        _Float16* C = (_Float16*)C0p + (long)bz * c0s;
        #pragma unroll
        for (int mi = 0; mi < 4; ++mi) {
            const int gmF = m0 + cm + mi * 16;
            const float4 bv = *(const float4*)&bias[gmF];
            #pragma unroll
            for (int ni = 0; ni < 4; ++ni) {
                const int gn = n0 + cn + ni * 16;
                C[(long)(gmF + 0) * LP + gn] = (_Float16)(acc[mi][ni][0] + bv.x);
                C[(long)(gmF + 1) * LP + gn] = (_Float16)(acc[mi][ni][1] + bv.y);
                C[(long)(gmF + 2) * LP + gn] = (_Float16)(acc[mi][ni][2] + bv.z);
                C[(long)(gmF + 3) * LP + gn] = (_Float16)(acc[mi][ni][3] + bv.w);
            }
        }
    }
}

// ---- weight converts ----
__global__ void conv_wtpg(const float* __restrict__ tw, const float* __restrict__ pw,
                          const float* __restrict__ gw, const float* __restrict__ tb,
                          const float* __restrict__ pb, const float* __restrict__ gb,
                          _Float16* __restrict__ W, float* __restrict__ btpg)
{
    const int i = blockIdx.x * 256 + threadIdx.x;     // float4 groups
    if (i < 393216) {
        const int e = i * 4;
        const int sz = 512 * 1024;
        const float* src = (e < sz) ? tw + e : ((e < 2 * sz) ? pw + e - sz : gw + e - 2 * sz);
        const float4 v = *(const float4*)src;
        union { _Float16 h[4]; uint2 u; } pk;
        pk.h[0] = (_Float16)v.x; pk.h[1] = (_Float16)v.y;
        pk.h[2] = (_Float16)v.z; pk.h[3] = (_Float16)v.w;
        *(uint2*)&W[e] = pk.u;
    }
    if (i < 512) btpg[i] = tb[i];
    else if (i < 1024) btpg[i] = pb[i - 512];
    else if (i < 1536) btpg[i] = gb[i - 1024];
}

__global__ void conv_wcat(const float* __restrict__ w1, const float* __restrict__ w2,
                          const float* __restrict__ b1, const float* __restrict__ b2,
                          _Float16* __restrict__ W, float* __restrict__ by)
{
    const int i = blockIdx.x * 256 + threadIdx.x;     // float4 groups
    if (i < 262144) {
        const int e = i * 4;
        const int c = e >> 10, k = e & 1023;
        const float* src = (k < 512) ? (w1 + c * 512 + k) : (w2 + c * 512 + k - 512);
        const float4 v = *(const float4*)src;
        union { _Float16 h[4]; uint2 u; } pk;
        pk.h[0] = (_Float16)v.x; pk.h[1] = (_Float16)v.y;
        pk.h[2] = (_Float16)v.z; pk.h[3] = (_Float16)v.w;
        *(uint2*)&W[e] = pk.u;
    }
    if (i < 1024) by[i] = b1[i] + b2[i];
}

// ---- x [b*8+n][c][hw] fp32 -> xtT [b][l=n*196+hw][c] fp16, LDS transpose ----
__global__ __launch_bounds__(256) void transpose_x(const float* __restrict__ x,
                                                   _Float16* __restrict__ xtT)
{
    __shared__ _Float16 t[128 * 201];   // pitch 201 -> 2-way max on read
    const int cs = blockIdx.x * 128;
    const int n = blockIdx.y, b = blockIdx.z;
    const float* src = x + ((long)(b * 8 + n) * 1024 + cs) * 196;
    for (int i = threadIdx.x; i < 128 * 49; i += 256) {
        const int r = i / 49, ch = i % 49;
        const float4 v = *(const float4*)&src[r * 196 + ch * 4];
        _Float16* tp = &t[r * 201 + ch * 4];
        tp[0] = (_Float16)v.x; tp[1] = (_Float16)v.y;
        tp[2] = (_Float16)v.z; tp[3] = (_Float16)v.w;
    }
    __syncthreads();
    _Float16* dst = xtT + (long)b * LP * 1024 + (long)n * 196 * 1024 + cs;
    for (int i = threadIdx.x; i < 196 * 16; i += 256) {
        const int hw = i >> 4, cg = i & 15;
        union { _Float16 h[8]; uint4 u; } pk;
        #pragma unroll
        for (int j = 0; j < 8; ++j) pk.h[j] = t[(cg * 8 + j) * 201 + hw];
        *(uint4*)&dst[(long)hw * 1024 + cg * 8] = pk.u;
    }
}

// ---- softmax over att rows (fp32 in), write fp16 in place (same row base),
//      zero-pad cols [1568,1664) which feed GEMM3's K dim ----
__global__ __launch_bounds__(256) void softmax_rows(float* __restrict__ att)
{
    const int blk = blockIdx.x;
    const int b = blk / LSZ, r = blk % LSZ;
    float* row = att + (long)b * LP * LP + (long)r * LP;
    _Float16* rb = (_Float16*)row;        // fp16 pitch = LP*2 elems, same base
    const int tid = threadIdx.x;

    float v[7];
    float mx = -1e30f;
    #pragma unroll
    for (int it = 0; it < 7; ++it) {
        const int m = tid + it * 256;
        v[it] = (m < LSZ) ? row[m] : -1e30f;
        mx = fmaxf(mx, v[it]);
    }
    __shared__ float red[256];
    red[tid] = mx; __syncthreads();
    for (int s = 128; s > 0; s >>= 1) {
        if (tid < s) red[tid] = fmaxf(red[tid], red[tid + s]);
        __syncthreads();
    }
    mx = red[0]; __syncthreads();

    float sum = 0.0f;
    #pragma unroll
    for (int it = 0; it < 7; ++it) {
        const int m = tid + it * 256;
        v[it] = (m < LSZ) ? __expf(v[it] - mx) : 0.0f;
        sum += v[it];
    }
    red[tid] = sum; __syncthreads();
    for (int s = 128; s > 0; s >>= 1) {
        if (tid < s) red[tid] += red[tid + s];
        __syncthreads();
    }
    const float inv = 1.0f / red[0];
    __syncthreads();   // all reads of fp32 row done before fp16 overwrite
    #pragma unroll
    for (int it = 0; it < 7; ++it) {
        const int m = tid + it * 256;
        if (m < LP) rb[m] = (m < LSZ) ? (_Float16)(v[it] * inv) : (_Float16)0.f;
    }
}

// ---- BN stats per channel over (b, l<1568) from y fp16 [1024, LP] ----
__global__ __launch_bounds__(256)
void bn_stats(const _Float16* __restrict__ y, const float* __restrict__ gamma,
              const float* __restrict__ beta, float* __restrict__ scale,
              float* __restrict__ shift)
{
    const int c = blockIdx.x;
    const int tid = threadIdx.x;
    float s1 = 0.f, s2 = 0.f;
    for (int idx = tid; idx < 8 * 196; idx += 256) {    // 1568 = 196*8 half8 chunks
        const int b = idx / 196, ch = idx % 196;
        const half8 v = *(const half8*)&y[(long)b * CCH * LP + (long)c * LP + ch * 8];
        #pragma unroll
        for (int j = 0; j < 8; ++j) { const float t = (float)v[j]; s1 += t; s2 += t * t; }
    }
    __shared__ float r1[256], r2[256];
    r1[tid] = s1; r2[tid] = s2; __syncthreads();
    for (int s = 128; s > 0; s >>= 1) {
        if (tid < s) { r1[tid] += r1[tid + s]; r2[tid] += r2[tid + s]; }
        __syncthreads();
    }
    if (tid == 0) {
        const float cnt = (float)(BATCH * LSZ);
        const float mean = r1[0] / cnt;
        const float var  = r2[0] / cnt - mean * mean;
        const float istd = rsqrtf(var + BN_EPS);
        const float sc = gamma[c] * istd;
        scale[c] = sc;
        shift[c] = beta[c] - mean * sc;
    }
}

// ---- out[b,n,c,hw] = y[b,c,n*196+hw]*scale[c]+shift[c] + x[b,n,c,hw] ----
__global__ void epilogue_k(const _Float16* __restrict__ y, const float* __restrict__ x,
                           const float* __restrict__ scale, const float* __restrict__ shift,
                           float* __restrict__ out)
{
    const long i4 = (long)blockIdx.x * 256 + threadIdx.x;
    const long idx = i4 * 4;
    if (idx >= TOT) return;
    const int b  = (int)(idx / ((long)SEQn * CCH * HWSZ));
    const int r  = (int)(idx % ((long)SEQn * CCH * HWSZ));
    const int n  = r / (CCH * HWSZ);
    const int r2 = r % (CCH * HWSZ);
    const int c  = r2 / HWSZ;
    const int hw = r2 % HWSZ;
    union { _Float16 h[4]; uint2 u; } v;
    v.u = *(const uint2*)&y[(long)b * CCH * LP + (long)c * LP + n * 196 + hw];
    const float4 xv = *(const float4*)&x[idx];
    const float sc = scale[c], sh = shift[c];
    float4 o;
    o.x = (float)v.h[0] * sc + sh + xv.x;
    o.y = (float)v.h[1] * sc + sh + xv.y;
    o.z = (float)v.h[2] * sc + sh + xv.z;
    o.w = (float)v.h[3] * sc + sh + xv.w;
    *(float4*)&out[idx] = o;
}

extern "C" void kernel_launch(void* const* d_in, const int* in_sizes, int n_in,
                              void* d_out, int out_size, void* d_ws, size_t ws_size,
                              hipStream_t stream)
{
    const float* x     = (const float*)d_in[0];
    const float* t_w   = (const float*)d_in[1];
    const float* t_b   = (const float*)d_in[2];
    const float* p_w   = (const float*)d_in[3];
    const float* p_b   = (const float*)d_in[4];
    const float* g_w   = (const float*)d_in[5];
    const float* g_b   = (const float*)d_in[6];
    const float* w1_w  = (const float*)d_in[7];
    const float* w1_b  = (const float*)d_in[8];
    const float* w2_w  = (const float*)d_in[9];
    const float* w2_b  = (const float*)d_in[10];
    const float* gamma = (const float*)d_in[11];
    const float* beta  = (const float*)d_in[12];
    float* out = (float*)d_out;

    // ---- workspace layout (bytes; all region sizes 1KB-multiples) ----
    char* ws = (char*)d_ws;
    _Float16* Wtpg = (_Float16*)ws;                      ws += (long)1536 * 1024 * 2;
    _Float16* Wcat = (_Float16*)ws;                      ws += (long)1024 * 1024 * 2;
    float*    btpg = (float*)ws;                         ws += 8192;
    float*    by   = (float*)ws;                         ws += 4096;
    float*    scale= (float*)ws;                         ws += 4096;
    float*    shift= (float*)ws;                         ws += 4096;
    _Float16* xtT  = (_Float16*)ws;                      ws += (long)BATCH * LP * 1024 * 2;
    _Float16* tTpT = (_Float16*)ws;                      ws += (long)BATCH * LP * 1024 * 2;
    _Float16* g    = (_Float16*)ws;                      ws += (long)BATCH * PPL * LP * 2;
    _Float16* gx2T = (_Float16*)ws;                      ws += (long)BATCH * LP * 1024 * 2;
    float*    att  = (float*)ws;                         ws += (long)BATCH * LP * LP * 4;
    _Float16* y    = (_Float16*)ws;                      ws += (long)BATCH * CCH * LP * 2;

    const long sXT  = (long)LP * 1024;       // xtT / tTpT / gx2T per-batch (f16 elems)
    const long sG   = (long)PPL * LP;
    const long sATT = (long)LP * LP;         // fp32 elems
    const long sAB  = (long)LP * 3328;       // att viewed as fp16 (pitch 3328)
    const long sY   = (long)CCH * LP;

    // 1) weight converts
    conv_wtpg<<<1536, 256, 0, stream>>>(t_w, p_w, g_w, t_b, p_b, g_b, Wtpg, btpg);
    conv_wcat<<<1024, 256, 0, stream>>>(w1_w, w2_w, w1_b, w2_b, Wcat, by);
    // 2) x -> xtT [b, l, c] fp16
    transpose_x<<<dim3(8, 8, 8), 256, 0, stream>>>(x, xtT);
    // 3) tpg projections: M=1536, N=1568(13), K=1024
    hgemm<0><<<dim3(13, 12, 8), 256, 0, stream>>>(
        Wtpg, 0, 1024, xtT, sXT, 1024,
        tTpT, sXT, g, sG, gx2T, sXT, btpg, 1024);
    // 4) att = tT @ pT^T: M=N=1568(13x13), K=512
    hgemm<1><<<dim3(13, 13, 8), 256, 0, stream>>>(
        tTpT, sXT, 512, tTpT + (long)LP * PPL, sXT, 512,
        att, sATT, nullptr, 0, nullptr, 0, nullptr, 512);
    // 5) softmax rows (fp32 -> fp16 in place, zero-pad K-tail)
    softmax_rows<<<BATCH * LSZ, 256, 0, stream>>>(att);
    // 6) x2T[l,q] = sum_m att_bf[l,m] g[q,m]: M=1568(13), N=512(4), K=1664
    hgemm<2><<<dim3(4, 13, 8), 256, 0, stream>>>(
        (const _Float16*)att, sAB, 3328, g, sG, LP,
        gx2T, sXT, nullptr, 0, nullptr, 0, nullptr, LP);
    // 7) y = [W1|W2] @ [gT|x2T]^T + (b1+b2): M=1024(8), N=1568(13), K=1024
    hgemm<3><<<dim3(13, 8, 8), 256, 0, stream>>>(
        Wcat, 0, 1024, gx2T, sXT, 1024,
        y, sY, nullptr, 0, nullptr, 0, by, 1024);
    // 8) BN stats
    bn_stats<<<CCH, 256, 0, stream>>>(y, gamma, beta, scale, shift);
    // 9) epilogue: BN apply + residual + layout restore
    epilogue_k<<<(int)(TOT / 4 / 256), 256, 0, stream>>>(y, x, scale, shift, out);
}

// Round 3
// 274.299 us; speedup vs baseline: 5.6252x; 1.0463x over previous
//
#include <hip/hip_runtime.h>

using half8   = __attribute__((ext_vector_type(8))) _Float16;
using floatx4 = __attribute__((ext_vector_type(4))) float;

constexpr int BATCH = 8, SEQn = 8, CCH = 1024, PPL = 512, HWSZ = 196;
constexpr int LSZ = 1568;            // SEQ * H * W
constexpr int LP  = 1664;            // padded L: 13*128
constexpr float BN_EPS = 1e-5f;
constexpr long TOT = (long)BATCH * SEQn * CCH * HWSZ;  // 12,845,056

// async global->LDS, 16B per lane; lds base wave-uniform
__device__ __forceinline__ void gload16(const void* g, void* lds) {
    __builtin_amdgcn_global_load_lds(
        (const __attribute__((address_space(1))) unsigned int*)g,
        (__attribute__((address_space(3))) unsigned int*)lds, 16, 0, 0);
}

#define MFMA_(a, b, c) __builtin_amdgcn_mfma_f32_16x16x32_f16((a), (b), (c), 0, 0, 0)
#define VM6 asm volatile("s_waitcnt vmcnt(6)" ::: "memory")
#define VM3 asm volatile("s_waitcnt vmcnt(3)" ::: "memory")
#define VM0 asm volatile("s_waitcnt vmcnt(0)" ::: "memory")

// =====================================================================
// 8-phase counted-vmcnt fp16 MFMA GEMM (T3+T4+T5 stack):
//  tile 256(M) x 128(N), BK=64, 512 threads = 8 waves (4M x 2N),
//  per-wave 64x64 out via 4x4 frags of 16x16x32_f16.
// LDS per buffer: A[2 ks][256][32], B[2 ks][128][32] (K-half sub-tiles,
//  each contiguous -> valid global_load_lds regions). Double-buffered: 96KB.
// Swizzle: staging source k-chunk pre-XOR f(r)=(r&3)^((r>>2)&3), ds_read
//  applies same XOR -> 8-lane groups hit 8 distinct bank-quads (rule #21).
// Phase p in {0..7}: buf=p>>2, ks=(p>>1)&1, nh=p&1. Each phase:
//  {ds_read frags; issue gloads; barrier; lgkmcnt(0); setprio(1); 8 MFMA;
//   setprio(0); [vmcnt gate on odd phases]; barrier}.
// Steady-state gates vmcnt(6); final iter peeled with (6,3,0).
// A/B stored [rows, K] row-major, K contiguous; all padded (no guards).
// EPI: 0 = tpg projections, 1 = att fp32, 2 = x2T, 3 = y
// =====================================================================
template<int EPI>
__global__ __launch_bounds__(512, 2)
void hgemm8(const _Float16* __restrict__ A, long asb, int lda,
            const _Float16* __restrict__ B, long bsb, int ldb,
            void* __restrict__ C0p, long c0s,
            void* __restrict__ C1p, long c1s,
            void* __restrict__ C2p, long c2s,
            const float* __restrict__ bias, int Mdim, int K)
{
    __shared__ __align__(16) _Float16 sh[49152];   // 96KB
    const int bz = blockIdx.z;
    const _Float16* Ab = A + (long)bz * asb;
    const _Float16* Bb = B + (long)bz * bsb;
    int m0 = blockIdx.y * 256;
    if (m0 + 256 > Mdim) m0 = Mdim - 256;          // overlapped last M-tile
    const int n0 = blockIdx.x * 128;
    const int tid = threadIdx.x;
    const int w = tid >> 6, ln = tid & 63;
    const int wm = w >> 1, wn = w & 1;
    const int wbase = w * 512;                     // staging dest per wave (halfs)

    // ---- staging thread constants ----
    const int rS = (w << 4) + (ln >> 2);           // 0..127 row within region-issue
    const int ccS = ln & 3;                        // dest chunk slot
    const int fS = ((ln >> 2) & 3) ^ (ln >> 4);    // f(rS)
    const int csrc = (ccS ^ fS) << 3;              // source k-offset (halfs)
    const _Float16* pA = Ab + (long)(m0 + rS) * lda + csrc;
    const _Float16* pB = Bb + (long)(n0 + rS) * ldb + csrc;

    // ---- fragment read offsets (halfs) ----
    const int fln = (ln & 3) ^ ((ln >> 2) & 3);
    const int slot = ((ln >> 4) ^ fln) << 3;
    const int arow = wm * 64 + (ln & 15);
    const int brow = wn * 64 + (ln & 15);
    const int aoff0 = (arow +  0) * 32 + slot;
    const int aoff1 = (arow + 16) * 32 + slot;
    const int aoff2 = (arow + 32) * 32 + slot;
    const int aoff3 = (arow + 48) * 32 + slot;
    const int boff0 = (brow +  0) * 32 + slot;
    const int boff1 = (brow + 16) * 32 + slot;
    const int boff2 = (brow + 32) * 32 + slot;
    const int boff3 = (brow + 48) * 32 + slot;

    floatx4 acc[4][4];
    #pragma unroll
    for (int i = 0; i < 4; ++i)
        #pragma unroll
        for (int j = 0; j < 4; ++j) acc[i][j] = (floatx4){0.f, 0.f, 0.f, 0.f};
    half8 af0, af1, af2, af3;

    const int NT = K >> 6;
    const int NITER = NT >> 1;

// region LDS bases: A: BUF*24576 + KS*8192 + CI*4096 ; B: BUF*24576 + 16384 + KS*4096
#define GA(T, KS, CI, BUF)                                                   \
    gload16(pA + ((CI) ? (long)128 * lda : 0L) + (long)(T) * 64 + (KS) * 32, \
            &sh[(BUF) * 24576 + (KS) * 8192 + (CI) * 4096 + wbase])
#define GB(T, KS, BUF)                                                       \
    gload16(pB + (long)(T) * 64 + (KS) * 32,                                 \
            &sh[(BUF) * 24576 + 16384 + (KS) * 4096 + wbase])

#define PH(BUF, KS, NH, ISSUES, GATE)                                        \
  {                                                                          \
    const int ab_ = (BUF) * 24576 + (KS) * 8192;                             \
    const int bb_ = (BUF) * 24576 + 16384 + (KS) * 4096;                     \
    if ((NH) == 0) {                                                         \
      af0 = *(const half8*)&sh[ab_ + aoff0];                                 \
      af1 = *(const half8*)&sh[ab_ + aoff1];                                 \
      af2 = *(const half8*)&sh[ab_ + aoff2];                                 \
      af3 = *(const half8*)&sh[ab_ + aoff3];                                 \
    }                                                                        \
    half8 bf0_ = *(const half8*)&sh[bb_ + ((NH) ? boff2 : boff0)];           \
    half8 bf1_ = *(const half8*)&sh[bb_ + ((NH) ? boff3 : boff1)];           \
    ISSUES                                                                   \
    __builtin_amdgcn_sched_barrier(0);                                       \
    __builtin_amdgcn_s_barrier();                                            \
    asm volatile("s_waitcnt lgkmcnt(0)" ::: "memory");                       \
    __builtin_amdgcn_sched_barrier(0);                                       \
    __builtin_amdgcn_s_setprio(1);                                           \
    acc[0][2*(NH)+0] = MFMA_(af0, bf0_, acc[0][2*(NH)+0]);                   \
    acc[1][2*(NH)+0] = MFMA_(af1, bf0_, acc[1][2*(NH)+0]);                   \
    acc[2][2*(NH)+0] = MFMA_(af2, bf0_, acc[2][2*(NH)+0]);                   \
    acc[3][2*(NH)+0] = MFMA_(af3, bf0_, acc[3][2*(NH)+0]);                   \
    acc[0][2*(NH)+1] = MFMA_(af0, bf1_, acc[0][2*(NH)+1]);                   \
    acc[1][2*(NH)+1] = MFMA_(af1, bf1_, acc[1][2*(NH)+1]);                   \
    acc[2][2*(NH)+1] = MFMA_(af2, bf1_, acc[2][2*(NH)+1]);                   \
    acc[3][2*(NH)+1] = MFMA_(af3, bf1_, acc[3][2*(NH)+1]);                   \
    __builtin_amdgcn_s_setprio(0);                                           \
    __builtin_amdgcn_sched_barrier(0);                                       \
    GATE;                                                                    \
    __builtin_amdgcn_s_barrier();                                            \
    __builtin_amdgcn_sched_barrier(0);                                       \
  }

    // ---- prologue: tile0 (buf0) fully + tile1 ks0 (buf1): 9 issues ----
    GA(0, 0, 0, 0); GA(0, 0, 1, 0); GB(0, 0, 0);
    GA(0, 1, 0, 0); GA(0, 1, 1, 0); GB(0, 1, 0);
    GA(1, 0, 0, 1); GA(1, 0, 1, 1); GB(1, 0, 1);
    asm volatile("s_waitcnt vmcnt(6)" ::: "memory");
    __builtin_amdgcn_sched_barrier(0);
    __builtin_amdgcn_s_barrier();
    __builtin_amdgcn_sched_barrier(0);

    // ---- main loop: tiles (2J, 2J+1) in (buf0, buf1) ----
    for (int J = 0; J < NITER - 1; ++J) {
        const int t1 = 2 * J + 1, t2 = 2 * J + 2, t3 = 2 * J + 3;
        PH(0, 0, 0, GA(t1, 1, 0, 1); GA(t1, 1, 1, 1);, )
        PH(0, 0, 1, GB(t1, 1, 1);, VM6)
        PH(0, 1, 0, GA(t2, 0, 0, 0); GA(t2, 0, 1, 0);, )
        PH(0, 1, 1, GB(t2, 0, 0);, VM6)
        PH(1, 0, 0, GA(t2, 1, 0, 0); GA(t2, 1, 1, 0);, )
        PH(1, 0, 1, GB(t2, 1, 0);, VM6)
        PH(1, 1, 0, GA(t3, 0, 0, 1); GA(t3, 0, 1, 1);, )
        PH(1, 1, 1, GB(t3, 0, 1);, VM6)
    }
    // ---- final iteration (no prefetch beyond NT; gates 6,3,0) ----
    {
        const int t1 = NT - 1;
        PH(0, 0, 0, GA(t1, 1, 0, 1); GA(t1, 1, 1, 1);, )
        PH(0, 0, 1, GB(t1, 1, 1);, VM6)
        PH(0, 1, 0, , )
        PH(0, 1, 1, , VM3)
        PH(1, 0, 0, , )
        PH(1, 0, 1, , VM0)
        PH(1, 1, 0, , )
        PH(1, 1, 1, , )
    }
#undef PH
#undef GA
#undef GB
    __builtin_amdgcn_sched_barrier(0);

    // ---- epilogue: C/D layout col = ln&15, row = (ln>>4)*4 + reg ----
    const int cm = wm * 64 + (ln >> 4) * 4;
    const int cn = wn * 64 + (ln & 15);

    if constexpr (EPI == 0) {
        if (m0 < 1024) {   // t or p -> transposed store [L, 512]
            _Float16* T = (_Float16*)C0p + (long)bz * c0s
                          + (m0 >= 512 ? (long)LP * PPL : 0);
            const int mb = m0 & 511;
            #pragma unroll
            for (int mi = 0; mi < 4; ++mi) {
                const int gmF = m0 + cm + mi * 16;
                const float4 bv = *(const float4*)&bias[gmF];
                const int gm = mb + cm + mi * 16;
                #pragma unroll
                for (int ni = 0; ni < 4; ++ni) {
                    const int gn = n0 + cn + ni * 16;
                    union { _Float16 h[4]; uint2 u; } pk;
                    pk.h[0] = (_Float16)(acc[mi][ni][0] + bv.x);
                    pk.h[1] = (_Float16)(acc[mi][ni][1] + bv.y);
                    pk.h[2] = (_Float16)(acc[mi][ni][2] + bv.z);
                    pk.h[3] = (_Float16)(acc[mi][ni][3] + bv.w);
                    *(uint2*)&T[(long)gn * PPL + gm] = pk.u;
                }
            }
        } else {           // g: normal [512, LP] + transposed into gx2T
            _Float16* G  = (_Float16*)C1p + (long)bz * c1s;
            _Float16* GT = (_Float16*)C2p + (long)bz * c2s;
            #pragma unroll
            for (int mi = 0; mi < 4; ++mi) {
                const int gmF = m0 + cm + mi * 16;
                const float4 bv = *(const float4*)&bias[gmF];
                const int q = gmF - 1024;
                #pragma unroll
                for (int ni = 0; ni < 4; ++ni) {
                    const int gn = n0 + cn + ni * 16;
                    union { _Float16 h[4]; uint2 u; } pk;
                    pk.h[0] = (_Float16)(acc[mi][ni][0] + bv.x);
                    pk.h[1] = (_Float16)(acc[mi][ni][1] + bv.y);
                    pk.h[2] = (_Float16)(acc[mi][ni][2] + bv.z);
                    pk.h[3] = (_Float16)(acc[mi][ni][3] + bv.w);
                    *(uint2*)&GT[(long)gn * 1024 + q] = pk.u;
                    const bool ok = gn < LSZ;   // zero-clamp: g feeds GEMM3's K
                    G[(long)(q + 0) * LP + gn] = ok ? pk.h[0] : (_Float16)0.f;
                    G[(long)(q + 1) * LP + gn] = ok ? pk.h[1] : (_Float16)0.f;
                    G[(long)(q + 2) * LP + gn] = ok ? pk.h[2] : (_Float16)0.f;
                    G[(long)(q + 3) * LP + gn] = ok ? pk.h[3] : (_Float16)0.f;
                }
            }
        }
    } else if constexpr (EPI == 1) {   // att fp32 [LP pitch]
        float* C = (float*)C0p + (long)bz * c0s;
        #pragma unroll
        for (int mi = 0; mi < 4; ++mi) {
            const int gm = m0 + cm + mi * 16;
            #pragma unroll
            for (int ni = 0; ni < 4; ++ni) {
                const int gn = n0 + cn + ni * 16;
                #pragma unroll
                for (int j = 0; j < 4; ++j)
                    C[(long)(gm + j) * LP + gn] = acc[mi][ni][j];
            }
        }
    } else if constexpr (EPI == 2) {   // x2T fp16 into gx2T[:, 512:1024]
        _Float16* C = (_Float16*)C0p + (long)bz * c0s + 512;
        #pragma unroll
        for (int mi = 0; mi < 4; ++mi) {
            const int gm = m0 + cm + mi * 16;
            #pragma unroll
            for (int ni = 0; ni < 4; ++ni) {
                const int gn = n0 + cn + ni * 16;
                #pragma unroll
                for (int j = 0; j < 4; ++j)
                    C[(long)(gm + j) * 1024 + gn] = (_Float16)acc[mi][ni][j];
            }
        }
    } else {                            // EPI 3: y fp16 + bias
        _Float16* C = (_Float16*)C0p + (long)bz * c0s;
        #pragma unroll
        for (int mi = 0; mi < 4; ++mi) {
            const int gmF = m0 + cm + mi * 16;
            const float4 bv = *(const float4*)&bias[gmF];
            #pragma unroll
            for (int ni = 0; ni < 4; ++ni) {
                const int gn = n0 + cn + ni * 16;
                C[(long)(gmF + 0) * LP + gn] = (_Float16)(acc[mi][ni][0] + bv.x);
                C[(long)(gmF + 1) * LP + gn] = (_Float16)(acc[mi][ni][1] + bv.y);
                C[(long)(gmF + 2) * LP + gn] = (_Float16)(acc[mi][ni][2] + bv.z);
                C[(long)(gmF + 3) * LP + gn] = (_Float16)(acc[mi][ni][3] + bv.w);
            }
        }
    }
}

// ---- weight converts ----
__global__ void conv_wtpg(const float* __restrict__ tw, const float* __restrict__ pw,
                          const float* __restrict__ gw, const float* __restrict__ tb,
                          const float* __restrict__ pb, const float* __restrict__ gb,
                          _Float16* __restrict__ W, float* __restrict__ btpg)
{
    const int i = blockIdx.x * 256 + threadIdx.x;     // float4 groups
    if (i < 393216) {
        const int e = i * 4;
        const int sz = 512 * 1024;
        const float* src = (e < sz) ? tw + e : ((e < 2 * sz) ? pw + e - sz : gw + e - 2 * sz);
        const float4 v = *(const float4*)src;
        union { _Float16 h[4]; uint2 u; } pk;
        pk.h[0] = (_Float16)v.x; pk.h[1] = (_Float16)v.y;
        pk.h[2] = (_Float16)v.z; pk.h[3] = (_Float16)v.w;
        *(uint2*)&W[e] = pk.u;
    }
    if (i < 512) btpg[i] = tb[i];
    else if (i < 1024) btpg[i] = pb[i - 512];
    else if (i < 1536) btpg[i] = gb[i - 1024];
}

__global__ void conv_wcat(const float* __restrict__ w1, const float* __restrict__ w2,
                          const float* __restrict__ b1, const float* __restrict__ b2,
                          _Float16* __restrict__ W, float* __restrict__ by)
{
    const int i = blockIdx.x * 256 + threadIdx.x;     // float4 groups
    if (i < 262144) {
        const int e = i * 4;
        const int c = e >> 10, k = e & 1023;
        const float* src = (k < 512) ? (w1 + c * 512 + k) : (w2 + c * 512 + k - 512);
        const float4 v = *(const float4*)src;
        union { _Float16 h[4]; uint2 u; } pk;
        pk.h[0] = (_Float16)v.x; pk.h[1] = (_Float16)v.y;
        pk.h[2] = (_Float16)v.z; pk.h[3] = (_Float16)v.w;
        *(uint2*)&W[e] = pk.u;
    }
    if (i < 1024) by[i] = b1[i] + b2[i];
}

// ---- x [b*8+n][c][hw] fp32 -> xtT [b][l=n*196+hw][c] fp16, LDS transpose ----
__global__ __launch_bounds__(256) void transpose_x(const float* __restrict__ x,
                                                   _Float16* __restrict__ xtT)
{
    __shared__ _Float16 t[128 * 201];
    const int cs = blockIdx.x * 128;
    const int n = blockIdx.y, b = blockIdx.z;
    const float* src = x + ((long)(b * 8 + n) * 1024 + cs) * 196;
    for (int i = threadIdx.x; i < 128 * 49; i += 256) {
        const int r = i / 49, ch = i % 49;
        const float4 v = *(const float4*)&src[r * 196 + ch * 4];
        _Float16* tp = &t[r * 201 + ch * 4];
        tp[0] = (_Float16)v.x; tp[1] = (_Float16)v.y;
        tp[2] = (_Float16)v.z; tp[3] = (_Float16)v.w;
    }
    __syncthreads();
    _Float16* dst = xtT + (long)b * LP * 1024 + (long)n * 196 * 1024 + cs;
    for (int i = threadIdx.x; i < 196 * 16; i += 256) {
        const int hw = i >> 4, cg = i & 15;
        union { _Float16 h[8]; uint4 u; } pk;
        #pragma unroll
        for (int j = 0; j < 8; ++j) pk.h[j] = t[(cg * 8 + j) * 201 + hw];
        *(uint4*)&dst[(long)hw * 1024 + cg * 8] = pk.u;
    }
}

// ---- softmax: att fp32 rows -> fp16 in place (same base), zero-pad K-tail ----
__global__ __launch_bounds__(256) void softmax_rows(float* __restrict__ att)
{
    const int blk = blockIdx.x;
    const int b = blk / LSZ, r = blk % LSZ;
    float* row = att + (long)b * LP * LP + (long)r * LP;
    _Float16* rb = (_Float16*)row;
    const int tid = threadIdx.x;

    float v[7];
    float mx = -1e30f;
    #pragma unroll
    for (int it = 0; it < 7; ++it) {
        const int m = tid + it * 256;
        v[it] = (m < LSZ) ? row[m] : -1e30f;
        mx = fmaxf(mx, v[it]);
    }
    __shared__ float red[256];
    red[tid] = mx; __syncthreads();
    for (int s = 128; s > 0; s >>= 1) {
        if (tid < s) red[tid] = fmaxf(red[tid], red[tid + s]);
        __syncthreads();
    }
    mx = red[0]; __syncthreads();

    float sum = 0.0f;
    #pragma unroll
    for (int it = 0; it < 7; ++it) {
        const int m = tid + it * 256;
        v[it] = (m < LSZ) ? __expf(v[it] - mx) : 0.0f;
        sum += v[it];
    }
    red[tid] = sum; __syncthreads();
    for (int s = 128; s > 0; s >>= 1) {
        if (tid < s) red[tid] += red[tid + s];
        __syncthreads();
    }
    const float inv = 1.0f / red[0];
    __syncthreads();   // all fp32 reads done before fp16 overwrite
    #pragma unroll
    for (int it = 0; it < 7; ++it) {
        const int m = tid + it * 256;
        if (m < LP) rb[m] = (m < LSZ) ? (_Float16)(v[it] * inv) : (_Float16)0.f;
    }
}

// ---- BN stats per channel over (b, l<1568) from y fp16 [1024, LP] ----
__global__ __launch_bounds__(256)
void bn_stats(const _Float16* __restrict__ y, const float* __restrict__ gamma,
              const float* __restrict__ beta, float* __restrict__ scale,
              float* __restrict__ shift)
{
    const int c = blockIdx.x;
    const int tid = threadIdx.x;
    float s1 = 0.f, s2 = 0.f;
    for (int idx = tid; idx < 8 * 196; idx += 256) {
        const int b = idx / 196, ch = idx % 196;
        const half8 v = *(const half8*)&y[(long)b * CCH * LP + (long)c * LP + ch * 8];
        #pragma unroll
        for (int j = 0; j < 8; ++j) { const float t = (float)v[j]; s1 += t; s2 += t * t; }
    }
    __shared__ float r1[256], r2[256];
    r1[tid] = s1; r2[tid] = s2; __syncthreads();
    for (int s = 128; s > 0; s >>= 1) {
        if (tid < s) { r1[tid] += r1[tid + s]; r2[tid] += r2[tid + s]; }
        __syncthreads();
    }
    if (tid == 0) {
        const float cnt = (float)(BATCH * LSZ);
        const float mean = r1[0] / cnt;
        const float var  = r2[0] / cnt - mean * mean;
        const float istd = rsqrtf(var + BN_EPS);
        const float sc = gamma[c] * istd;
        scale[c] = sc;
        shift[c] = beta[c] - mean * sc;
    }
}

// ---- out[b,n,c,hw] = y[b,c,n*196+hw]*scale[c]+shift[c] + x[b,n,c,hw] ----
__global__ void epilogue_k(const _Float16* __restrict__ y, const float* __restrict__ x,
                           const float* __restrict__ scale, const float* __restrict__ shift,
                           float* __restrict__ out)
{
    const long i4 = (long)blockIdx.x * 256 + threadIdx.x;
    const long idx = i4 * 4;
    if (idx >= TOT) return;
    const int b  = (int)(idx / ((long)SEQn * CCH * HWSZ));
    const int r  = (int)(idx % ((long)SEQn * CCH * HWSZ));
    const int n  = r / (CCH * HWSZ);
    const int r2 = r % (CCH * HWSZ);
    const int c  = r2 / HWSZ;
    const int hw = r2 % HWSZ;
    union { _Float16 h[4]; uint2 u; } v;
    v.u = *(const uint2*)&y[(long)b * CCH * LP + (long)c * LP + n * 196 + hw];
    const float4 xv = *(const float4*)&x[idx];
    const float sc = scale[c], sh = shift[c];
    float4 o;
    o.x = (float)v.h[0] * sc + sh + xv.x;
    o.y = (float)v.h[1] * sc + sh + xv.y;
    o.z = (float)v.h[2] * sc + sh + xv.z;
    o.w = (float)v.h[3] * sc + sh + xv.w;
    *(float4*)&out[idx] = o;
}

extern "C" void kernel_launch(void* const* d_in, const int* in_sizes, int n_in,
                              void* d_out, int out_size, void* d_ws, size_t ws_size,
                              hipStream_t stream)
{
    const float* x     = (const float*)d_in[0];
    const float* t_w   = (const float*)d_in[1];
    const float* t_b   = (const float*)d_in[2];
    const float* p_w   = (const float*)d_in[3];
    const float* p_b   = (const float*)d_in[4];
    const float* g_w   = (const float*)d_in[5];
    const float* g_b   = (const float*)d_in[6];
    const float* w1_w  = (const float*)d_in[7];
    const float* w1_b  = (const float*)d_in[8];
    const float* w2_w  = (const float*)d_in[9];
    const float* w2_b  = (const float*)d_in[10];
    const float* gamma = (const float*)d_in[11];
    const float* beta  = (const float*)d_in[12];
    float* out = (float*)d_out;

    // ---- workspace layout (~189 MB) ----
    char* wsp = (char*)d_ws;
    _Float16* Wtpg = (_Float16*)wsp;                 wsp += (long)1536 * 1024 * 2;
    _Float16* Wcat = (_Float16*)wsp;                 wsp += (long)1024 * 1024 * 2;
    float*    btpg = (float*)wsp;                    wsp += 8192;
    float*    by   = (float*)wsp;                    wsp += 4096;
    float*    scale= (float*)wsp;                    wsp += 4096;
    float*    shift= (float*)wsp;                    wsp += 4096;
    _Float16* xtT  = (_Float16*)wsp;                 wsp += (long)BATCH * LP * 1024 * 2;
    _Float16* tTpT = (_Float16*)wsp;                 wsp += (long)BATCH * 2 * LP * 512 * 2;
    _Float16* g    = (_Float16*)wsp;                 wsp += (long)BATCH * 512 * LP * 2;
    _Float16* gx2T = (_Float16*)wsp;                 wsp += (long)BATCH * LP * 1024 * 2;
    float*    att  = (float*)wsp;                    wsp += (long)BATCH * LP * LP * 4;
    _Float16* y    = xtT;    // alias: xtT dead after G1, G4 runs after

    const long sXT  = (long)LP * 1024;     // xtT / gx2T per-batch (halfs)
    const long sTP  = (long)2 * LP * 512;  // tTpT per-batch
    const long sG   = (long)512 * LP;
    const long sATT = (long)LP * LP;       // fp32 elems
    const long sAF16= (long)2 * LP * LP;   // att viewed as halfs
    const long sY   = (long)CCH * LP;

    // 1) weight converts
    conv_wtpg<<<1536, 256, 0, stream>>>(t_w, p_w, g_w, t_b, p_b, g_b, Wtpg, btpg);
    conv_wcat<<<1024, 256, 0, stream>>>(w1_w, w2_w, w1_b, w2_b, Wcat, by);
    // 2) x -> xtT [b, l, c] fp16
    transpose_x<<<dim3(8, 8, 8), 256, 0, stream>>>(x, xtT);
    // 3) tpg projections: M=1536, N=1664, K=1024
    hgemm8<0><<<dim3(13, 6, 8), 512, 0, stream>>>(
        Wtpg, 0, 1024, xtT, sXT, 1024,
        tTpT, sTP, g, sG, gx2T, sXT, btpg, 1536, 1024);
    // 4) att = tT @ pT^T: M=1664 (overlapped), N=1664, K=512
    hgemm8<1><<<dim3(13, 7, 8), 512, 0, stream>>>(
        tTpT, sTP, 512, tTpT + (long)LP * 512, sTP, 512,
        att, sATT, nullptr, 0, nullptr, 0, nullptr, LP, 512);
    // 5) softmax rows (fp32 -> fp16 in place, zero-pad K-tail)
    softmax_rows<<<BATCH * LSZ, 256, 0, stream>>>(att);
    // 6) x2T[l,q] = sum_m att[l,m] g[q,m]: M=1664 (overlapped), N=512, K=1664
    hgemm8<2><<<dim3(4, 7, 8), 512, 0, stream>>>(
        (const _Float16*)att, sAF16, 2 * LP, g, sG, LP,
        gx2T, sXT, nullptr, 0, nullptr, 0, nullptr, LP, LP);
    // 7) y = [W1|W2] @ [gT|x2T]^T + (b1+b2): M=1024, N=1664, K=1024
    hgemm8<3><<<dim3(13, 4, 8), 512, 0, stream>>>(
        Wcat, 0, 1024, gx2T, sXT, 1024,
        y, sY, nullptr, 0, nullptr, 0, by, 1024, 1024);
    // 8) BN stats
    bn_stats<<<CCH, 256, 0, stream>>>(y, gamma, beta, scale, shift);
    // 9) BN apply + residual + layout restore
    epilogue_k<<<(int)(TOT / 4 / 256), 256, 0, stream>>>(y, x, scale, shift, out);
}

// Round 4
// 261.717 us; speedup vs baseline: 5.8956x; 1.0481x over previous
//
#include <hip/hip_runtime.h>

using half8   = __attribute__((ext_vector_type(8))) _Float16;
using floatx4 = __attribute__((ext_vector_type(4))) float;

constexpr int BATCH = 8, SEQn = 8, CCH = 1024, PPL = 512, HWSZ = 196;
constexpr int LSZ = 1568;            // SEQ * H * W
constexpr int LP  = 1664;            // padded L: 13*128
constexpr float BN_EPS = 1e-5f;
constexpr long TOT = (long)BATCH * SEQn * CCH * HWSZ;  // 12,845,056

// async global->LDS, 16B per lane; lds base must be wave-uniform (HW adds lane*16B)
__device__ __forceinline__ void gload16(const void* g, void* lds) {
    __builtin_amdgcn_global_load_lds(
        (const __attribute__((address_space(1))) unsigned int*)g,
        (__attribute__((address_space(3))) unsigned int*)lds, 16, 0, 0);
}

#define MFMA_(a, b, c) __builtin_amdgcn_mfma_f32_16x16x32_f16((a), (b), (c), 0, 0, 0)
#define VM6 asm volatile("s_waitcnt vmcnt(6)" ::: "memory")
#define VM0 asm volatile("s_waitcnt vmcnt(0)" ::: "memory")

// =====================================================================
// fp16 MFMA GEMM, counted-vmcnt pipeline, m201-ratio phases:
//  tile 256(M) x 128(N), BK=32, 256 threads = 4 waves (2M x 2N),
//  per-wave 128x64 via 8x4 frags of 16x16x32_f16 -> 16 MFMA per phase.
//  LDS: 3 buffers x (A 256x32 + B 128x32) halfs = 72KB -> 2 blocks/CU
//  (independent blocks overlap each other's barrier drains).
//  Pipeline: while computing tile t (2 phases), stage tile t+2 (6 issues);
//  gate vmcnt(6) once per tile; peeled tail gates (0).
//  Swizzle (rule #21 both-sides): row r granule c holds src chunk c^((r>>1)&3);
//  ds_read slot = (ln>>4)^((ln>>1)&3) -> 2-way max (free).
// A/B stored [rows, K] row-major, K contiguous; buffers padded (no guards).
// EPI: 0 = tpg projections, 1 = att fp32, 2 = x2T, 3 = y
// =====================================================================
template<int EPI>
__global__ __launch_bounds__(256, 2)
void hgemm8(const _Float16* __restrict__ A, long asb, int lda,
            const _Float16* __restrict__ B, long bsb, int ldb,
            void* __restrict__ C0p, long c0s,
            void* __restrict__ C1p, long c1s,
            void* __restrict__ C2p, long c2s,
            const float* __restrict__ bias, int Mdim, int K)
{
    __shared__ __align__(16) _Float16 sh[36864];   // 72KB: 3 bufs x 12288 halfs
    const int bz = blockIdx.z;
    const _Float16* Ab = A + (long)bz * asb;
    const _Float16* Bb = B + (long)bz * bsb;
    int m0 = blockIdx.y * 256;
    if (m0 + 256 > Mdim) m0 = Mdim - 256;          // overlapped last M-tile
    const int n0 = blockIdx.x * 128;
    const int tid = threadIdx.x;
    const int w = tid >> 6, ln = tid & 63;
    const int wm = w >> 1, wn = w & 1;

    // ---- staging constants: thread t covers granule t of each 4KB issue ----
    const int srow = tid >> 2;                     // 0..63 row within issue
    const int schunk = (tid & 3) ^ ((tid >> 3) & 3); // src chunk = dest ^ f(row)
    const _Float16* pA = Ab + (long)(m0 + srow) * lda + schunk * 8;
    const _Float16* pB = Bb + (long)(n0 + srow) * ldb + schunk * 8;
    const long lda64 = (long)64 * lda, ldb64 = (long)64 * ldb;
    const int sdw = w * 512;                       // wave-uniform dest (halfs)

    // ---- fragment read offsets (halfs); slot undoes the staging XOR ----
    const int soff = ((ln >> 4) ^ ((ln >> 1) & 3)) * 8;
    int aoff[8], boff[4];
    #pragma unroll
    for (int mi = 0; mi < 8; ++mi)
        aoff[mi] = (wm * 128 + mi * 16 + (ln & 15)) * 32 + soff;
    #pragma unroll
    for (int ni = 0; ni < 4; ++ni)
        boff[ni] = 8192 + (wn * 64 + ni * 16 + (ln & 15)) * 32 + soff;

    floatx4 acc[8][4];
    #pragma unroll
    for (int i = 0; i < 8; ++i)
        #pragma unroll
        for (int j = 0; j < 4; ++j) acc[i][j] = (floatx4){0.f, 0.f, 0.f, 0.f};
    half8 bf0, bf1, bf2, bf3;   // B frags persist h0 -> h1

    const int NT = K >> 5;      // BK=32

#define PH(H, ISSUES, GATE)                                                  \
  {                                                                          \
    half8 af0 = *(const half8*)&sh[cur + aoff[4*(H)+0]];                     \
    half8 af1 = *(const half8*)&sh[cur + aoff[4*(H)+1]];                     \
    half8 af2 = *(const half8*)&sh[cur + aoff[4*(H)+2]];                     \
    half8 af3 = *(const half8*)&sh[cur + aoff[4*(H)+3]];                     \
    if ((H) == 0) {                                                          \
      bf0 = *(const half8*)&sh[cur + boff[0]];                               \
      bf1 = *(const half8*)&sh[cur + boff[1]];                               \
      bf2 = *(const half8*)&sh[cur + boff[2]];                               \
      bf3 = *(const half8*)&sh[cur + boff[3]];                               \
    }                                                                        \
    ISSUES                                                                   \
    __builtin_amdgcn_sched_barrier(0);                                       \
    __builtin_amdgcn_s_barrier();                                            \
    asm volatile("s_waitcnt lgkmcnt(0)" ::: "memory");                       \
    __builtin_amdgcn_sched_barrier(0);                                       \
    __builtin_amdgcn_s_setprio(1);                                           \
    acc[4*(H)+0][0] = MFMA_(af0, bf0, acc[4*(H)+0][0]);                      \
    acc[4*(H)+1][0] = MFMA_(af1, bf0, acc[4*(H)+1][0]);                      \
    acc[4*(H)+2][0] = MFMA_(af2, bf0, acc[4*(H)+2][0]);                      \
    acc[4*(H)+3][0] = MFMA_(af3, bf0, acc[4*(H)+3][0]);                      \
    acc[4*(H)+0][1] = MFMA_(af0, bf1, acc[4*(H)+0][1]);                      \
    acc[4*(H)+1][1] = MFMA_(af1, bf1, acc[4*(H)+1][1]);                      \
    acc[4*(H)+2][1] = MFMA_(af2, bf1, acc[4*(H)+2][1]);                      \
    acc[4*(H)+3][1] = MFMA_(af3, bf1, acc[4*(H)+3][1]);                      \
    acc[4*(H)+0][2] = MFMA_(af0, bf2, acc[4*(H)+0][2]);                      \
    acc[4*(H)+1][2] = MFMA_(af1, bf2, acc[4*(H)+1][2]);                      \
    acc[4*(H)+2][2] = MFMA_(af2, bf2, acc[4*(H)+2][2]);                      \
    acc[4*(H)+3][2] = MFMA_(af3, bf2, acc[4*(H)+3][2]);                      \
    acc[4*(H)+0][3] = MFMA_(af0, bf3, acc[4*(H)+0][3]);                      \
    acc[4*(H)+1][3] = MFMA_(af1, bf3, acc[4*(H)+1][3]);                      \
    acc[4*(H)+2][3] = MFMA_(af2, bf3, acc[4*(H)+2][3]);                      \
    acc[4*(H)+3][3] = MFMA_(af3, bf3, acc[4*(H)+3][3]);                      \
    __builtin_amdgcn_s_setprio(0);                                           \
    __builtin_amdgcn_sched_barrier(0);                                       \
    GATE;                                                                    \
    __builtin_amdgcn_s_barrier();                                            \
    __builtin_amdgcn_sched_barrier(0);                                       \
  }

    // ---- prologue: stage tile0 -> buf0, tile1 -> buf1 (12 issues) ----
    #pragma unroll
    for (int i = 0; i < 4; ++i) gload16(pA + i * lda64, &sh[i * 2048 + sdw]);
    #pragma unroll
    for (int i = 0; i < 2; ++i) gload16(pB + i * ldb64, &sh[8192 + i * 2048 + sdw]);
    #pragma unroll
    for (int i = 0; i < 4; ++i) gload16(pA + 32 + i * lda64, &sh[12288 + i * 2048 + sdw]);
    #pragma unroll
    for (int i = 0; i < 2; ++i) gload16(pB + 32 + i * ldb64, &sh[20480 + i * 2048 + sdw]);
    VM6;
    __builtin_amdgcn_sched_barrier(0);
    __builtin_amdgcn_s_barrier();
    __builtin_amdgcn_sched_barrier(0);

    int cur = 0, nxt = 12288, stg = 24576;
    const _Float16* pA_s = pA + 64;
    const _Float16* pB_s = pB + 64;

    // ---- main loop: compute tile t, stage tile t+2 into stg ----
    for (int t = 0; t < NT - 2; ++t) {
        PH(0,
           gload16(pA_s,             &sh[stg + sdw]);
           gload16(pA_s + lda64,     &sh[stg + 2048 + sdw]);
           gload16(pB_s,             &sh[stg + 8192 + sdw]);, )
        PH(1,
           gload16(pA_s + 2 * lda64, &sh[stg + 4096 + sdw]);
           gload16(pA_s + 3 * lda64, &sh[stg + 6144 + sdw]);
           gload16(pB_s + ldb64,     &sh[stg + 10240 + sdw]);, VM6)
        const int tmp = cur; cur = nxt; nxt = stg; stg = tmp;
        pA_s += 32; pB_s += 32;
    }
    // ---- tail: tile NT-2 (drain), tile NT-1 ----
    PH(0, , )
    PH(1, , VM0)
    { const int tmp = cur; cur = nxt; nxt = stg; stg = tmp; }
    PH(0, , )
    PH(1, , )
#undef PH
    __builtin_amdgcn_sched_barrier(0);

    // ---- epilogue: C/D layout col = ln&15, row = (ln>>4)*4 + reg ----
    const int cm = wm * 128 + (ln >> 4) * 4;
    const int cn = wn * 64 + (ln & 15);

    if constexpr (EPI == 0) {
        if (m0 < 1024) {   // t or p -> transposed store [L, 512]
            _Float16* T = (_Float16*)C0p + (long)bz * c0s
                          + (m0 >= 512 ? (long)LP * PPL : 0);
            const int mb = m0 & 511;
            #pragma unroll
            for (int mi = 0; mi < 8; ++mi) {
                const int gmF = m0 + cm + mi * 16;
                const float4 bv = *(const float4*)&bias[gmF];
                const int gm = mb + cm + mi * 16;
                #pragma unroll
                for (int ni = 0; ni < 4; ++ni) {
                    const int gn = n0 + cn + ni * 16;
                    union { _Float16 h[4]; uint2 u; } pk;
                    pk.h[0] = (_Float16)(acc[mi][ni][0] + bv.x);
                    pk.h[1] = (_Float16)(acc[mi][ni][1] + bv.y);
                    pk.h[2] = (_Float16)(acc[mi][ni][2] + bv.z);
                    pk.h[3] = (_Float16)(acc[mi][ni][3] + bv.w);
                    *(uint2*)&T[(long)gn * PPL + gm] = pk.u;
                }
            }
        } else {           // g: normal [512, LP] + transposed into gx2T
            _Float16* G  = (_Float16*)C1p + (long)bz * c1s;
            _Float16* GT = (_Float16*)C2p + (long)bz * c2s;
            #pragma unroll
            for (int mi = 0; mi < 8; ++mi) {
                const int gmF = m0 + cm + mi * 16;
                const float4 bv = *(const float4*)&bias[gmF];
                const int q = gmF - 1024;
                #pragma unroll
                for (int ni = 0; ni < 4; ++ni) {
                    const int gn = n0 + cn + ni * 16;
                    union { _Float16 h[4]; uint2 u; } pk;
                    pk.h[0] = (_Float16)(acc[mi][ni][0] + bv.x);
                    pk.h[1] = (_Float16)(acc[mi][ni][1] + bv.y);
                    pk.h[2] = (_Float16)(acc[mi][ni][2] + bv.z);
                    pk.h[3] = (_Float16)(acc[mi][ni][3] + bv.w);
                    *(uint2*)&GT[(long)gn * 1024 + q] = pk.u;
                    const bool ok = gn < LSZ;   // zero-clamp: g feeds GEMM3's K
                    G[(long)(q + 0) * LP + gn] = ok ? pk.h[0] : (_Float16)0.f;
                    G[(long)(q + 1) * LP + gn] = ok ? pk.h[1] : (_Float16)0.f;
                    G[(long)(q + 2) * LP + gn] = ok ? pk.h[2] : (_Float16)0.f;
                    G[(long)(q + 3) * LP + gn] = ok ? pk.h[3] : (_Float16)0.f;
                }
            }
        }
    } else if constexpr (EPI == 1) {   // att fp32 [LP pitch]
        float* C = (float*)C0p + (long)bz * c0s;
        #pragma unroll
        for (int mi = 0; mi < 8; ++mi) {
            const int gm = m0 + cm + mi * 16;
            #pragma unroll
            for (int ni = 0; ni < 4; ++ni) {
                const int gn = n0 + cn + ni * 16;
                #pragma unroll
                for (int j = 0; j < 4; ++j)
                    C[(long)(gm + j) * LP + gn] = acc[mi][ni][j];
            }
        }
    } else if constexpr (EPI == 2) {   // x2T fp16 into gx2T[:, 512:1024]
        _Float16* C = (_Float16*)C0p + (long)bz * c0s + 512;
        #pragma unroll
        for (int mi = 0; mi < 8; ++mi) {
            const int gm = m0 + cm + mi * 16;
            #pragma unroll
            for (int ni = 0; ni < 4; ++ni) {
                const int gn = n0 + cn + ni * 16;
                #pragma unroll
                for (int j = 0; j < 4; ++j)
                    C[(long)(gm + j) * 1024 + gn] = (_Float16)acc[mi][ni][j];
            }
        }
    } else {                            // EPI 3: y fp16 + bias
        _Float16* C = (_Float16*)C0p + (long)bz * c0s;
        #pragma unroll
        for (int mi = 0; mi < 8; ++mi) {
            const int gmF = m0 + cm + mi * 16;
            const float4 bv = *(const float4*)&bias[gmF];
            #pragma unroll
            for (int ni = 0; ni < 4; ++ni) {
                const int gn = n0 + cn + ni * 16;
                C[(long)(gmF + 0) * LP + gn] = (_Float16)(acc[mi][ni][0] + bv.x);
                C[(long)(gmF + 1) * LP + gn] = (_Float16)(acc[mi][ni][1] + bv.y);
                C[(long)(gmF + 2) * LP + gn] = (_Float16)(acc[mi][ni][2] + bv.z);
                C[(long)(gmF + 3) * LP + gn] = (_Float16)(acc[mi][ni][3] + bv.w);
            }
        }
    }
}

// ---- weight converts ----
__global__ void conv_wtpg(const float* __restrict__ tw, const float* __restrict__ pw,
                          const float* __restrict__ gw, const float* __restrict__ tb,
                          const float* __restrict__ pb, const float* __restrict__ gb,
                          _Float16* __restrict__ W, float* __restrict__ btpg)
{
    const int i = blockIdx.x * 256 + threadIdx.x;     // float4 groups
    if (i < 393216) {
        const int e = i * 4;
        const int sz = 512 * 1024;
        const float* src = (e < sz) ? tw + e : ((e < 2 * sz) ? pw + e - sz : gw + e - 2 * sz);
        const float4 v = *(const float4*)src;
        union { _Float16 h[4]; uint2 u; } pk;
        pk.h[0] = (_Float16)v.x; pk.h[1] = (_Float16)v.y;
        pk.h[2] = (_Float16)v.z; pk.h[3] = (_Float16)v.w;
        *(uint2*)&W[e] = pk.u;
    }
    if (i < 512) btpg[i] = tb[i];
    else if (i < 1024) btpg[i] = pb[i - 512];
    else if (i < 1536) btpg[i] = gb[i - 1024];
}

__global__ void conv_wcat(const float* __restrict__ w1, const float* __restrict__ w2,
                          const float* __restrict__ b1, const float* __restrict__ b2,
                          _Float16* __restrict__ W, float* __restrict__ by)
{
    const int i = blockIdx.x * 256 + threadIdx.x;     // float4 groups
    if (i < 262144) {
        const int e = i * 4;
        const int c = e >> 10, k = e & 1023;
        const float* src = (k < 512) ? (w1 + c * 512 + k) : (w2 + c * 512 + k - 512);
        const float4 v = *(const float4*)src;
        union { _Float16 h[4]; uint2 u; } pk;
        pk.h[0] = (_Float16)v.x; pk.h[1] = (_Float16)v.y;
        pk.h[2] = (_Float16)v.z; pk.h[3] = (_Float16)v.w;
        *(uint2*)&W[e] = pk.u;
    }
    if (i < 1024) by[i] = b1[i] + b2[i];
}

// ---- x [b*8+n][c][hw] fp32 -> xtT [b][l=n*196+hw][c] fp16, LDS transpose ----
__global__ __launch_bounds__(256) void transpose_x(const float* __restrict__ x,
                                                   _Float16* __restrict__ xtT)
{
    __shared__ _Float16 t[128 * 201];
    const int cs = blockIdx.x * 128;
    const int n = blockIdx.y, b = blockIdx.z;
    const float* src = x + ((long)(b * 8 + n) * 1024 + cs) * 196;
    for (int i = threadIdx.x; i < 128 * 49; i += 256) {
        const int r = i / 49, ch = i % 49;
        const float4 v = *(const float4*)&src[r * 196 + ch * 4];
        _Float16* tp = &t[r * 201 + ch * 4];
        tp[0] = (_Float16)v.x; tp[1] = (_Float16)v.y;
        tp[2] = (_Float16)v.z; tp[3] = (_Float16)v.w;
    }
    __syncthreads();
    _Float16* dst = xtT + (long)b * LP * 1024 + (long)n * 196 * 1024 + cs;
    for (int i = threadIdx.x; i < 196 * 16; i += 256) {
        const int hw = i >> 4, cg = i & 15;
        union { _Float16 h[8]; uint4 u; } pk;
        #pragma unroll
        for (int j = 0; j < 8; ++j) pk.h[j] = t[(cg * 8 + j) * 201 + hw];
        *(uint4*)&dst[(long)hw * 1024 + cg * 8] = pk.u;
    }
}

// ---- softmax: att fp32 rows -> fp16 in place (same base), zero-pad K-tail ----
__global__ __launch_bounds__(256) void softmax_rows(float* __restrict__ att)
{
    const int blk = blockIdx.x;
    const int b = blk / LSZ, r = blk % LSZ;
    float* row = att + (long)b * LP * LP + (long)r * LP;
    _Float16* rb = (_Float16*)row;
    const int tid = threadIdx.x;

    float v[7];
    float mx = -1e30f;
    #pragma unroll
    for (int it = 0; it < 7; ++it) {
        const int m = tid + it * 256;
        v[it] = (m < LSZ) ? row[m] : -1e30f;
        mx = fmaxf(mx, v[it]);
    }
    __shared__ float red[256];
    red[tid] = mx; __syncthreads();
    for (int s = 128; s > 0; s >>= 1) {
        if (tid < s) red[tid] = fmaxf(red[tid], red[tid + s]);
        __syncthreads();
    }
    mx = red[0]; __syncthreads();

    float sum = 0.0f;
    #pragma unroll
    for (int it = 0; it < 7; ++it) {
        const int m = tid + it * 256;
        v[it] = (m < LSZ) ? __expf(v[it] - mx) : 0.0f;
        sum += v[it];
    }
    red[tid] = sum; __syncthreads();
    for (int s = 128; s > 0; s >>= 1) {
        if (tid < s) red[tid] += red[tid + s];
        __syncthreads();
    }
    const float inv = 1.0f / red[0];
    __syncthreads();   // all fp32 reads done before fp16 overwrite
    #pragma unroll
    for (int it = 0; it < 7; ++it) {
        const int m = tid + it * 256;
        if (m < LP) rb[m] = (m < LSZ) ? (_Float16)(v[it] * inv) : (_Float16)0.f;
    }
}

// ---- BN stats per channel over (b, l<1568) from y fp16 [1024, LP] ----
__global__ __launch_bounds__(256)
void bn_stats(const _Float16* __restrict__ y, const float* __restrict__ gamma,
              const float* __restrict__ beta, float* __restrict__ scale,
              float* __restrict__ shift)
{
    const int c = blockIdx.x;
    const int tid = threadIdx.x;
    float s1 = 0.f, s2 = 0.f;
    for (int idx = tid; idx < 8 * 196; idx += 256) {
        const int b = idx / 196, ch = idx % 196;
        const half8 v = *(const half8*)&y[(long)b * CCH * LP + (long)c * LP + ch * 8];
        #pragma unroll
        for (int j = 0; j < 8; ++j) { const float t = (float)v[j]; s1 += t; s2 += t * t; }
    }
    __shared__ float r1[256], r2[256];
    r1[tid] = s1; r2[tid] = s2; __syncthreads();
    for (int s = 128; s > 0; s >>= 1) {
        if (tid < s) { r1[tid] += r1[tid + s]; r2[tid] += r2[tid + s]; }
        __syncthreads();
    }
    if (tid == 0) {
        const float cnt = (float)(BATCH * LSZ);
        const float mean = r1[0] / cnt;
        const float var  = r2[0] / cnt - mean * mean;
        const float istd = rsqrtf(var + BN_EPS);
        const float sc = gamma[c] * istd;
        scale[c] = sc;
        shift[c] = beta[c] - mean * sc;
    }
}

// ---- out[b,n,c,hw] = y[b,c,n*196+hw]*scale[c]+shift[c] + x[b,n,c,hw] ----
__global__ void epilogue_k(const _Float16* __restrict__ y, const float* __restrict__ x,
                           const float* __restrict__ scale, const float* __restrict__ shift,
                           float* __restrict__ out)
{
    const long i4 = (long)blockIdx.x * 256 + threadIdx.x;
    const long idx = i4 * 4;
    if (idx >= TOT) return;
    const int b  = (int)(idx / ((long)SEQn * CCH * HWSZ));
    const int r  = (int)(idx % ((long)SEQn * CCH * HWSZ));
    const int n  = r / (CCH * HWSZ);
    const int r2 = r % (CCH * HWSZ);
    const int c  = r2 / HWSZ;
    const int hw = r2 % HWSZ;
    union { _Float16 h[4]; uint2 u; } v;
    v.u = *(const uint2*)&y[(long)b * CCH * LP + (long)c * LP + n * 196 + hw];
    const float4 xv = *(const float4*)&x[idx];
    const float sc = scale[c], sh = shift[c];
    float4 o;
    o.x = (float)v.h[0] * sc + sh + xv.x;
    o.y = (float)v.h[1] * sc + sh + xv.y;
    o.z = (float)v.h[2] * sc + sh + xv.z;
    o.w = (float)v.h[3] * sc + sh + xv.w;
    *(float4*)&out[idx] = o;
}

extern "C" void kernel_launch(void* const* d_in, const int* in_sizes, int n_in,
                              void* d_out, int out_size, void* d_ws, size_t ws_size,
                              hipStream_t stream)
{
    const float* x     = (const float*)d_in[0];
    const float* t_w   = (const float*)d_in[1];
    const float* t_b   = (const float*)d_in[2];
    const float* p_w   = (const float*)d_in[3];
    const float* p_b   = (const float*)d_in[4];
    const float* g_w   = (const float*)d_in[5];
    const float* g_b   = (const float*)d_in[6];
    const float* w1_w  = (const float*)d_in[7];
    const float* w1_b  = (const float*)d_in[8];
    const float* w2_w  = (const float*)d_in[9];
    const float* w2_b  = (const float*)d_in[10];
    const float* gamma = (const float*)d_in[11];
    const float* beta  = (const float*)d_in[12];
    float* out = (float*)d_out;

    // ---- workspace layout ----
    char* wsp = (char*)d_ws;
    _Float16* Wtpg = (_Float16*)wsp;                 wsp += (long)1536 * 1024 * 2;
    _Float16* Wcat = (_Float16*)wsp;                 wsp += (long)1024 * 1024 * 2;
    float*    btpg = (float*)wsp;                    wsp += 8192;
    float*    by   = (float*)wsp;                    wsp += 4096;
    float*    scale= (float*)wsp;                    wsp += 4096;
    float*    shift= (float*)wsp;                    wsp += 4096;
    _Float16* xtT  = (_Float16*)wsp;                 wsp += (long)BATCH * LP * 1024 * 2;
    _Float16* tTpT = (_Float16*)wsp;                 wsp += (long)BATCH * 2 * LP * 512 * 2;
    _Float16* g    = (_Float16*)wsp;                 wsp += (long)BATCH * 512 * LP * 2;
    _Float16* gx2T = (_Float16*)wsp;                 wsp += (long)BATCH * LP * 1024 * 2;
    float*    att  = (float*)wsp;                    wsp += (long)BATCH * LP * LP * 4;
    _Float16* y    = xtT;    // alias: xtT dead after G1, G4 runs after

    const long sXT  = (long)LP * 1024;     // xtT / gx2T per-batch (halfs)
    const long sTP  = (long)2 * LP * 512;  // tTpT per-batch
    const long sG   = (long)512 * LP;
    const long sATT = (long)LP * LP;       // fp32 elems
    const long sAF16= (long)2 * LP * LP;   // att viewed as halfs
    const long sY   = (long)CCH * LP;

    // 1) weight converts
    conv_wtpg<<<1536, 256, 0, stream>>>(t_w, p_w, g_w, t_b, p_b, g_b, Wtpg, btpg);
    conv_wcat<<<1024, 256, 0, stream>>>(w1_w, w2_w, w1_b, w2_b, Wcat, by);
    // 2) x -> xtT [b, l, c] fp16
    transpose_x<<<dim3(8, 8, 8), 256, 0, stream>>>(x, xtT);
    // 3) tpg projections: M=1536, N=1664, K=1024
    hgemm8<0><<<dim3(13, 6, 8), 256, 0, stream>>>(
        Wtpg, 0, 1024, xtT, sXT, 1024,
        tTpT, sTP, g, sG, gx2T, sXT, btpg, 1536, 1024);
    // 4) att = tT @ pT^T: M=1664 (overlapped), N=1664, K=512
    hgemm8<1><<<dim3(13, 7, 8), 256, 0, stream>>>(
        tTpT, sTP, 512, tTpT + (long)LP * 512, sTP, 512,
        att, sATT, nullptr, 0, nullptr, 0, nullptr, LP, 512);
    // 5) softmax rows (fp32 -> fp16 in place, zero-pad K-tail)
    softmax_rows<<<BATCH * LSZ, 256, 0, stream>>>(att);
    // 6) x2T[l,q] = sum_m att[l,m] g[q,m]: M=1664 (overlapped), N=512, K=1664
    hgemm8<2><<<dim3(4, 7, 8), 256, 0, stream>>>(
        (const _Float16*)att, sAF16, 2 * LP, g, sG, LP,
        gx2T, sXT, nullptr, 0, nullptr, 0, nullptr, LP, LP);
    // 7) y = [W1|W2] @ [gT|x2T]^T + (b1+b2): M=1024, N=1664, K=1024
    hgemm8<3><<<dim3(13, 4, 8), 256, 0, stream>>>(
        Wcat, 0, 1024, gx2T, sXT, 1024,
        y, sY, nullptr, 0, nullptr, 0, by, 1024, 1024);
    // 8) BN stats
    bn_stats<<<CCH, 256, 0, stream>>>(y, gamma, beta, scale, shift);
    // 9) BN apply + residual + layout restore
    epilogue_k<<<(int)(TOT / 4 / 256), 256, 0, stream>>>(y, x, scale, shift, out);
}